// Round 5
// baseline (140.158 us; speedup 1.0000x reference)
//
#include <hip/hip_runtime.h>
#include <hip/hip_bf16.h>

typedef unsigned short u16;
typedef unsigned int u32;

#define BATCH 4
#define NLEN 2048
#define DIM 512
#define LDSK 40   // 32 + 8 pad (u16)
#define LDSB 72   // 64 + 8 pad (u16)

typedef __attribute__((ext_vector_type(8))) __bf16 bf16x8;
typedef __attribute__((ext_vector_type(4))) float f32x4;

__device__ __forceinline__ u16 f32_to_bf16(float f) {
  union { float f; u32 u; } v; v.f = f;
  u32 u = v.u;
  return (u16)((u + 0x7FFFu + ((u >> 16) & 1u)) >> 16);
}
__device__ __forceinline__ u32 pk2(float lo, float hi) {
  return (u32)f32_to_bf16(lo) | ((u32)f32_to_bf16(hi) << 16);
}
__device__ __forceinline__ void stage8_f32(u16* dst, const float* src) {
  float4 a = *(const float4*)src;
  float4 b = *(const float4*)(src + 4);
  uint4 o;
  o.x = pk2(a.x, a.y); o.y = pk2(a.z, a.w);
  o.z = pk2(b.x, b.y); o.w = pk2(b.z, b.w);
  *(uint4*)dst = o;
}
__device__ __forceinline__ void stage16_f32(u16* dst, const float* src) {
  stage8_f32(dst, src); stage8_f32(dst + 8, src + 8);
}
__device__ __forceinline__ void stage8_bf16(u16* dst, const u16* src) {
  *(uint4*)dst = *(const uint4*)src;
}
__device__ __forceinline__ void stage16_bf16(u16* dst, const u16* src) {
  *(uint4*)dst = *(const uint4*)src;
  *(uint4*)(dst + 8) = *(const uint4*)(src + 8);
}

template <int MR, int NR>
__device__ __forceinline__ void mma_tile(const u16* As, const u16* Bs, f32x4 acc[MR][NR],
                                         int wm, int wn, int lr, int lk) {
  bf16x8 af[MR], bfr[NR];
#pragma unroll
  for (int m = 0; m < MR; ++m)
    af[m] = *(const bf16x8*)(As + (wm + m * 16 + lr) * LDSK + lk);
#pragma unroll
  for (int n = 0; n < NR; ++n)
    bfr[n] = *(const bf16x8*)(Bs + (wn + n * 16 + lr) * LDSK + lk);
#pragma unroll
  for (int m = 0; m < MR; ++m)
#pragma unroll
    for (int n = 0; n < NR; ++n)
      acc[m][n] = __builtin_amdgcn_mfma_f32_16x16x32_bf16(af[m], bfr[n], acc[m][n], 0, 0, 0);
}

// ---------------- K1: q projection (64x128 tiles, 512 blocks) ----------------
__global__ __launch_bounds__(256) void k_qproj(const float* __restrict__ query,
                                               const float* __restrict__ W_in,
                                               u16* __restrict__ qp, u16* __restrict__ qt) {
  __shared__ u16 As[64 * LDSK];
  __shared__ u16 Bs[128 * LDSK];
  __shared__ u16 tbuf[128][72];
  const int t = threadIdx.x;
  const int lane = t & 63, wid = t >> 6;
  const int wm = (wid >> 1) * 32, wn = (wid & 1) * 64;
  const int lr = lane & 15, lk = (lane >> 4) * 8;
  const int trow4 = t >> 2, tseg = (t & 3) * 8;
  const int trow2 = t >> 1, thalf = (t & 1) * 16;
  const int rbase = blockIdx.y * 64;
  const int cbase = blockIdx.x * 128;
  const int rg = rbase + trow4;
  const int bb = rg >> 11, nn = rg & 2047;
  const float* aRow = query + (size_t)(nn * BATCH + bb) * DIM + tseg;
  const float* bRow = W_in + (size_t)(cbase + trow2) * DIM + thalf;
  f32x4 acc[2][4] = {};
  for (int k0 = 0; k0 < DIM; k0 += 32) {
    stage8_f32(As + trow4 * LDSK + tseg, aRow + k0);
    stage16_f32(Bs + trow2 * LDSK + thalf, bRow + k0);
    __syncthreads();
    mma_tile<2, 4>(As, Bs, acc, wm, wn, lr, lk);
    __syncthreads();
  }
#pragma unroll
  for (int m = 0; m < 2; ++m)
#pragma unroll
    for (int n = 0; n < 4; ++n)
#pragma unroll
      for (int j = 0; j < 4; ++j) {
        int rl = wm + m * 16 + (lane >> 4) * 4 + j;
        int cl = wn + n * 16 + lr;
        u16 v = f32_to_bf16(acc[m][n][j]);
        qp[(size_t)(rbase + rl) * DIM + cbase + cl] = v;
        tbuf[cl][rl] = v;
      }
  __syncthreads();
  const int bb0 = rbase >> 11, nbase = rbase & 2047;
#pragma unroll
  for (int i = 0; i < 4; ++i) {
    int idx = t + i * 256;
    int dl = idx >> 3, c = idx & 7;
    uint4 v = *(const uint4*)&tbuf[dl][c * 8];
    *(uint4*)(qt + (size_t)(bb0 * DIM + cbase + dl) * NLEN + nbase + c * 8) = v;
  }
}

// ---------------- K2: scores (64x128 tiles) -> packed lower-tri bf16 128-tiles ----------------
__global__ __launch_bounds__(256) void k_scores(const u16* __restrict__ qp,
                                                u16* __restrict__ swf) {
  const int mt = blockIdx.x;
  const int nt = blockIdx.y;
  const int b = blockIdx.z;
  if (mt > (nt >> 1)) return;
  __shared__ u16 As[64 * LDSK];
  __shared__ u16 Bs[128 * LDSK];
  const int t = threadIdx.x;
  const int lane = t & 63, wid = t >> 6;
  const int wm = (wid >> 1) * 32, wn = (wid & 1) * 64;
  const int lr = lane & 15, lk = (lane >> 4) * 8;
  const int trow4 = t >> 2, tseg = (t & 3) * 8;
  const int trow2 = t >> 1, thalf = (t & 1) * 16;
  const u16* aRow = qp + (size_t)(b * NLEN + nt * 64 + trow4) * DIM + tseg;
  const u16* bRow = qp + (size_t)(b * NLEN + mt * 128 + trow2) * DIM + thalf;
  f32x4 acc[2][4] = {};
  for (int k0 = 0; k0 < DIM; k0 += 32) {
    stage8_bf16(As + trow4 * LDSK + tseg, aRow + k0);
    stage16_bf16(Bs + trow2 * LDSK + thalf, bRow + k0);
    __syncthreads();
    mma_tile<2, 4>(As, Bs, acc, wm, wn, lr, lk);
    __syncthreads();
  }
  const int NT = nt >> 1;
  u16* wtile = swf + ((size_t)(b * 136 + NT * (NT + 1) / 2 + mt) << 14);
  const int rowoff = (nt & 1) * 64;
#pragma unroll
  for (int m = 0; m < 2; ++m)
#pragma unroll
    for (int n = 0; n < 4; ++n)
#pragma unroll
      for (int j = 0; j < 4; ++j) {
        int rl = wm + m * 16 + (lane >> 4) * 4 + j;
        int cl = wn + n * 16 + lr;
        wtile[(rowoff + rl) * 128 + cl] = f32_to_bf16(acc[m][n][j]);
      }
}

// ---------------- K3: softmax (+64 trailing blocks convert W_out -> bf16) ----------------
__global__ __launch_bounds__(256) void k_softmax(u16* __restrict__ swf, float* __restrict__ w,
                                                 const float* __restrict__ W_out,
                                                 u16* __restrict__ wob) {
  const int n = blockIdx.x, b = blockIdx.y;
  const int t = threadIdx.x;
  if (n >= NLEN) {
    int g = ((n - NLEN) * 4 + b) * 256 + t;  // 0..16383
#pragma unroll
    for (int i = 0; i < 4; ++i) {
      int e = g * 32 + i * 8;
      stage8_f32(wob + e, W_out + e);
    }
    return;
  }
  float* wrow = w + ((size_t)b * NLEN + n) * NLEN;
  const int nt = n >> 7;
  const size_t tb = ((size_t)(b * 136 + nt * (nt + 1) / 2) << 14) + ((size_t)(n & 127) << 7);
  __shared__ float srow[NLEN];
  __shared__ float red[4];
  if (n == 0) {
    for (int i = t; i < NLEN / 4; i += 256) ((float4*)wrow)[i] = float4{0, 0, 0, 0};
    if (t < 16) ((uint4*)(swf + tb))[t] = uint4{0, 0, 0, 0};
    return;
  }
  const int lane = t & 63, wid = t >> 6;
  const int nchunk = (nt + 1) * 16;
  float mx = -1e38f;
  for (int idx = t; idx < nchunk; idx += 256) {
    const int mt = idx >> 4, c = idx & 15;
    uint4 rv = *(const uint4*)(swf + tb + ((size_t)mt << 14) + c * 8);
    int m0 = mt * 128 + c * 8;
    u32 wds[4] = {rv.x, rv.y, rv.z, rv.w};
#pragma unroll
    for (int wi = 0; wi < 4; ++wi) {
      float v0 = __uint_as_float(wds[wi] << 16);
      float v1 = __uint_as_float(wds[wi] & 0xffff0000u);
      int m = m0 + wi * 2;
      srow[m] = v0; srow[m + 1] = v1;
      if (m < n) mx = fmaxf(mx, v0);
      if (m + 1 < n) mx = fmaxf(mx, v1);
    }
  }
#pragma unroll
  for (int off = 32; off; off >>= 1) mx = fmaxf(mx, __shfl_xor(mx, off));
  if (lane == 0) red[wid] = mx;
  __syncthreads();
  mx = fmaxf(fmaxf(red[0], red[1]), fmaxf(red[2], red[3]));
  float sum = 0.f;
  for (int m = t; m < n; m += 256) {
    float e = __expf(srow[m] - mx);
    srow[m] = e;
    sum += e;
  }
#pragma unroll
  for (int off = 32; off; off >>= 1) sum += __shfl_xor(sum, off);
  __syncthreads();
  if (lane == 0) red[wid] = sum;
  __syncthreads();
  float inv = 1.0f / (red[0] + red[1] + red[2] + red[3]);
  {
    int m0 = t * 8;
    float vals[8];
#pragma unroll
    for (int e = 0; e < 8; ++e) { int m = m0 + e; vals[e] = (m < n) ? srow[m] * inv : 0.f; }
    ((float4*)wrow)[t * 2] = float4{vals[0], vals[1], vals[2], vals[3]};
    ((float4*)wrow)[t * 2 + 1] = float4{vals[4], vals[5], vals[6], vals[7]};
  }
  for (int idx = t; idx < nchunk; idx += 256) {
    const int mt = idx >> 4, c = idx & 15;
    int m0 = mt * 128 + c * 8;
    u32 wo[4];
#pragma unroll
    for (int wi = 0; wi < 4; ++wi) {
      int m = m0 + wi * 2;
      float v0 = (m < n) ? srow[m] * inv : 0.f;
      float v1 = (m + 1 < n) ? srow[m + 1] * inv : 0.f;
      wo[wi] = (u32)f32_to_bf16(v0) | ((u32)f32_to_bf16(v1) << 16);
    }
    *(uint4*)(swf + tb + ((size_t)mt << 14) + c * 8) = uint4{wo[0], wo[1], wo[2], wo[3]};
  }
}

// ---------------- K4: mix, row-split load balance, direct bf16 output ----------------
template <int ROWS>
__device__ __forceinline__ void mix_body(u16* As, u16* Bs,
                                         const u16* __restrict__ swf,
                                         const u16* __restrict__ qt,
                                         u16* __restrict__ amix,
                                         int b, int dt, int nt, int seg) {
  constexpr int MR = (ROWS == 128) ? 4 : 2;
  constexpr int NR = 4;
  const int t = threadIdx.x;
  const int lane = t & 63, wid = t >> 6;
  const int wm = (wid >> 1) * (ROWS / 2), wn = (wid & 1) * 64;
  const int lr = lane & 15, lk = (lane >> 4) * 8;
  const int trow2 = t >> 1, thalf = (t & 1) * 16;
  // A staging geometry: 2 thr/row (ROWS=128) or 4 thr/row (ROWS=64)
  const int ar = (ROWS == 128) ? (t >> 1) : (t >> 2);
  const int ac = (ROWS == 128) ? ((t & 1) * 16) : ((t & 3) * 8);
  const size_t tribase = (size_t)(b * 136 + nt * (nt + 1) / 2) << 14;
  const int rowloc = seg * ROWS;
  const u16* bRow = qt + (size_t)(b * DIM + dt * 128 + trow2) * NLEN + thalf;
  f32x4 acc[MR][NR] = {};
  const int nsteps = (nt + 1) * 4;
  for (int kstep = 0; kstep < nsteps; ++kstep) {
    const int k0 = kstep * 32;
    const int mt = k0 >> 7;
    const u16* aSrc = swf + tribase + ((size_t)mt << 14) + (rowloc + ar) * 128 + (k0 & 127) + ac;
    if (ROWS == 128) stage16_bf16(As + ar * LDSK + ac, aSrc);
    else stage8_bf16(As + ar * LDSK + ac, aSrc);
    stage16_bf16(Bs + trow2 * LDSK + thalf, bRow + k0);
    __syncthreads();
    mma_tile<MR, NR>(As, Bs, acc, wm, wn, lr, lk);
    __syncthreads();
  }
#pragma unroll
  for (int m = 0; m < MR; ++m)
#pragma unroll
    for (int n = 0; n < NR; ++n)
#pragma unroll
      for (int j2 = 0; j2 < 4; ++j2) {
        int row = nt * 128 + rowloc + wm + m * 16 + (lane >> 4) * 4 + j2;
        int col = dt * 128 + wn + n * 16 + lr;
        amix[(size_t)(b * NLEN + row) * DIM + col] = f32_to_bf16(acc[m][n][j2]);
      }
}

__global__ __launch_bounds__(256) void k_mix(const u16* __restrict__ swf,
                                             const u16* __restrict__ qt,
                                             u16* __restrict__ amix) {
  __shared__ u16 As[128 * LDSK];
  __shared__ u16 Bs[128 * LDSK];
  const int bid = blockIdx.x;      // 448 = 28 j-slots x 16 (b,dt); heavy j first
  const int j = bid >> 4;
  const int bdt = bid & 15;
  const int b = bdt >> 2, dt = bdt & 3;
  if (j < 24) {
    const int nt = 15 - (j >> 1), seg = j & 1;
    mix_body<64>(As, Bs, swf, qt, amix, b, dt, nt, seg);
  } else {
    const int nt = 27 - j;
    mix_body<128>(As, Bs, swf, qt, amix, b, dt, nt, 0);
  }
}

// ---------------- K5: out = selu([amix,q] . wob^T), 128x64 tiles, BK=64 ----------------
__global__ __launch_bounds__(256) void k_out(const u16* __restrict__ amix,
                                             const u16* __restrict__ qp,
                                             const u16* __restrict__ wob,
                                             float* __restrict__ out) {
  __shared__ u16 As[128 * LDSB];
  __shared__ u16 Bs[64 * LDSB];
  const int et = blockIdx.x;   // 8 col tiles of 64
  const int rt = blockIdx.y;   // 64 row tiles of 128
  const int t = threadIdx.x;
  const int lane = t & 63, wid = t >> 6;
  const int wm = (wid >> 1) * 64, wn = (wid & 1) * 32;
  const int lr = lane & 15, lk = (lane >> 4) * 8;
  const int rbase = rt * 128;
  const int ar = t >> 3, ac = (t & 7) * 8;
  const int br = t >> 2, bc = (t & 3) * 16;
  const u16* aMix = amix + (size_t)rbase * DIM;
  const u16* aQ = qp + (size_t)rbase * DIM;
  const u16* bW = wob + (size_t)(et * 64 + br) * (2 * DIM) + bc;
  f32x4 acc[4][2] = {};
  for (int k0 = 0; k0 < 2 * DIM; k0 += 64) {
    const u16* asrc = (k0 < DIM) ? (aMix + k0) : (aQ + (k0 - DIM));
#pragma unroll
    for (int i = 0; i < 4; ++i)
      *(uint4*)(As + (ar + i * 32) * LDSB + ac) =
          *(const uint4*)(asrc + (size_t)(ar + i * 32) * DIM + ac);
    *(uint4*)(Bs + br * LDSB + bc) = *(const uint4*)(bW + k0);
    *(uint4*)(Bs + br * LDSB + bc + 8) = *(const uint4*)(bW + k0 + 8);
    __syncthreads();
#pragma unroll
    for (int kk = 0; kk < 64; kk += 32) {
      bf16x8 af[4], bfr[2];
#pragma unroll
      for (int m = 0; m < 4; ++m)
        af[m] = *(const bf16x8*)(As + (wm + m * 16 + lr) * LDSB + kk + lk);
#pragma unroll
      for (int n = 0; n < 2; ++n)
        bfr[n] = *(const bf16x8*)(Bs + (wn + n * 16 + lr) * LDSB + kk + lk);
#pragma unroll
      for (int m = 0; m < 4; ++m)
#pragma unroll
        for (int n = 0; n < 2; ++n)
          acc[m][n] = __builtin_amdgcn_mfma_f32_16x16x32_bf16(af[m], bfr[n], acc[m][n], 0, 0, 0);
    }
    __syncthreads();
  }
  const float sc = 1.0507009873554805f;
  const float al = 1.6732632423543772f;
#pragma unroll
  for (int m = 0; m < 4; ++m)
#pragma unroll
    for (int n = 0; n < 2; ++n)
#pragma unroll
      for (int j = 0; j < 4; ++j) {
        int row = rbase + wm + m * 16 + (lane >> 4) * 4 + j;
        int col = et * 64 + wn + n * 16 + lr;
        int b2 = row >> 11, n2 = row & 2047;
        float v = acc[m][n][j];
        v = (v > 0.f) ? sc * v : sc * al * (__expf(v) - 1.f);
        out[(size_t)(n2 * BATCH + b2) * DIM + col] = v;
      }
}

extern "C" void kernel_launch(void* const* d_in, const int* in_sizes, int n_in,
                              void* d_out, int out_size, void* d_ws, size_t ws_size,
                              hipStream_t stream) {
  const float* query = (const float*)d_in[0];
  const float* W_in = (const float*)d_in[1];
  const float* W_out = (const float*)d_in[2];
  float* out0 = (float*)d_out;                   // [NLEN][BATCH][DIM] f32
  float* w = out0 + (size_t)NLEN * BATCH * DIM;  // weights [BATCH][NLEN][NLEN] f32

  const size_t PSZ = (size_t)BATCH * NLEN * DIM;
  u16* qp = (u16*)d_ws;            // [B][N][D] bf16
  u16* qt = qp + PSZ;              // [B][D][N] bf16
  u16* amix = qt + PSZ;            // [B][N][D] bf16 (mix, folded)
  u16* swf = amix + PSZ;           // packed tri tiles [B][136][128][128] bf16
  u16* wob = swf + (size_t)BATCH * 136 * 16384;  // W_out bf16 [512][1024]

  dim3 blk(256);
  k_qproj<<<dim3(DIM / 128, (BATCH * NLEN) / 64), blk, 0, stream>>>(query, W_in, qp, qt);
  k_scores<<<dim3(16, 32, BATCH), blk, 0, stream>>>(qp, swf);
  k_softmax<<<dim3(NLEN + 16, BATCH), blk, 0, stream>>>(swf, w, W_out, wob);
  k_mix<<<dim3(448), blk, 0, stream>>>(swf, qt, amix);
  k_out<<<dim3(8, 64), blk, 0, stream>>>(amix, qp, wob, out0);
}

// Round 6
// 124.207 us; speedup vs baseline: 1.1284x; 1.1284x over previous
//
#include <hip/hip_runtime.h>
#include <hip/hip_bf16.h>

typedef unsigned short u16;
typedef unsigned int u32;

#define BATCH 4
#define NLEN 2048
#define DIM 512
#define LDSK 40   // 32 + 8 pad (u16) -- k_qproj only

typedef __attribute__((ext_vector_type(8))) __bf16 bf16x8;
typedef __attribute__((ext_vector_type(4))) float f32x4;

typedef const __attribute__((address_space(1))) void gv_t;
typedef __attribute__((address_space(3))) void lv_t;

__device__ __forceinline__ u16 f32_to_bf16(float f) {
  union { float f; u32 u; } v; v.f = f;
  u32 u = v.u;
  return (u16)((u + 0x7FFFu + ((u >> 16) & 1u)) >> 16);
}
__device__ __forceinline__ u32 pk2(float lo, float hi) {
  return (u32)f32_to_bf16(lo) | ((u32)f32_to_bf16(hi) << 16);
}
__device__ __forceinline__ void stage8_f32(u16* dst, const float* src) {
  float4 a = *(const float4*)src;
  float4 b = *(const float4*)(src + 4);
  uint4 o;
  o.x = pk2(a.x, a.y); o.y = pk2(a.z, a.w);
  o.z = pk2(b.x, b.y); o.w = pk2(b.z, b.w);
  *(uint4*)dst = o;
}
__device__ __forceinline__ void stage16_f32(u16* dst, const float* src) {
  stage8_f32(dst, src); stage8_f32(dst + 8, src + 8);
}
__device__ __forceinline__ u32 addpk_bf16(u32 a, u32 b) {
  float a0 = __uint_as_float(a << 16), a1 = __uint_as_float(a & 0xffff0000u);
  float b0 = __uint_as_float(b << 16), b1 = __uint_as_float(b & 0xffff0000u);
  return pk2(a0 + b0, a1 + b1);
}

// async global -> LDS staging of a [..][64]-bf16 tile slab; lds layout linear [row][64].
// Each wave-load moves 8 rows (1 KiB): lane l -> row (l>>3), elems (l&7)*8.
template <int NRPW>  // rows per wave (32 for 128-row tile, 16 for 64-row tile)
__device__ __forceinline__ void glds_rows(const u16* gsrc, size_t gstride, u16* lds,
                                          int wrow0, int lane) {
  const int r = lane >> 3;
  const int c = (lane & 7) * 8;
#pragma unroll
  for (int i = 0; i < NRPW; i += 8) {
    const int row = wrow0 + i + r;
    __builtin_amdgcn_global_load_lds((gv_t*)(gsrc + (size_t)row * gstride + c),
                                     (lv_t*)(lds + row * 64 + c), 16, 0, 0);
  }
}

// ---------------- K1: q projection (64x128 tiles, 512 blocks) ----------------
__global__ __launch_bounds__(256) void k_qproj(const float* __restrict__ query,
                                               const float* __restrict__ W_in,
                                               u16* __restrict__ qp, u16* __restrict__ qt) {
  __shared__ u16 As[64 * LDSK];
  __shared__ u16 Bs[128 * LDSK];
  __shared__ u16 tbuf[128][72];
  const int t = threadIdx.x;
  const int lane = t & 63, wid = t >> 6;
  const int wm = (wid >> 1) * 32, wn = (wid & 1) * 64;
  const int lr = lane & 15, lk = (lane >> 4) * 8;
  const int trow4 = t >> 2, tseg = (t & 3) * 8;
  const int trow2 = t >> 1, thalf = (t & 1) * 16;
  const int rbase = blockIdx.y * 64;
  const int cbase = blockIdx.x * 128;
  const int rg = rbase + trow4;
  const int bb = rg >> 11, nn = rg & 2047;
  const float* aRow = query + (size_t)(nn * BATCH + bb) * DIM + tseg;
  const float* bRow = W_in + (size_t)(cbase + trow2) * DIM + thalf;
  f32x4 acc[2][4] = {};
  for (int k0 = 0; k0 < DIM; k0 += 32) {
    stage8_f32(As + trow4 * LDSK + tseg, aRow + k0);
    stage16_f32(Bs + trow2 * LDSK + thalf, bRow + k0);
    __syncthreads();
    bf16x8 af[2], bfr[4];
#pragma unroll
    for (int m = 0; m < 2; ++m) af[m] = *(const bf16x8*)(As + (wm + m * 16 + lr) * LDSK + lk);
#pragma unroll
    for (int n = 0; n < 4; ++n) bfr[n] = *(const bf16x8*)(Bs + (wn + n * 16 + lr) * LDSK + lk);
#pragma unroll
    for (int m = 0; m < 2; ++m)
#pragma unroll
      for (int n = 0; n < 4; ++n)
        acc[m][n] = __builtin_amdgcn_mfma_f32_16x16x32_bf16(af[m], bfr[n], acc[m][n], 0, 0, 0);
    __syncthreads();
  }
#pragma unroll
  for (int m = 0; m < 2; ++m)
#pragma unroll
    for (int n = 0; n < 4; ++n)
#pragma unroll
      for (int j = 0; j < 4; ++j) {
        int rl = wm + m * 16 + (lane >> 4) * 4 + j;
        int cl = wn + n * 16 + lr;
        u16 v = f32_to_bf16(acc[m][n][j]);
        qp[(size_t)(rbase + rl) * DIM + cbase + cl] = v;
        tbuf[cl][rl] = v;
      }
  __syncthreads();
  const int bb0 = rbase >> 11, nbase = rbase & 2047;
#pragma unroll
  for (int i = 0; i < 4; ++i) {
    int idx = t + i * 256;
    int dl = idx >> 3, c = idx & 7;
    uint4 v = *(const uint4*)&tbuf[dl][c * 8];
    *(uint4*)(qt + (size_t)(bb0 * DIM + cbase + dl) * NLEN + nbase + c * 8) = v;
  }
}

// ---------------- K2: scores, m97 structure (128x128, BK=64, glds) ----------------
__global__ __launch_bounds__(256) void k_scores(const u16* __restrict__ qp,
                                                u16* __restrict__ swf) {
  const int tri = blockIdx.x;  // 0..135 lower-tri tile index
  const int b = blockIdx.y;
  int nt = 0, cacc = 0;
  while (cacc + nt + 1 <= tri) { cacc += nt + 1; ++nt; }
  const int mt = tri - cacc;
  __shared__ u16 As[128 * 64];
  __shared__ u16 Bs[128 * 64];
  const int t = threadIdx.x;
  const int lane = t & 63, wid = t >> 6;
  const int wm = (wid >> 1) * 64, wn = (wid & 1) * 64;
  const int lr = lane & 15, lk = (lane >> 4) * 8;
  const u16* ag = qp + (size_t)(b * NLEN + nt * 128) * DIM;
  const u16* bg = qp + (size_t)(b * NLEN + mt * 128) * DIM;
  f32x4 acc[4][4] = {};
  for (int k0 = 0; k0 < DIM; k0 += 64) {
    glds_rows<32>(ag + k0, DIM, As, wid * 32, lane);
    glds_rows<32>(bg + k0, DIM, Bs, wid * 32, lane);
    __syncthreads();
#pragma unroll
    for (int kk = 0; kk < 64; kk += 32) {
      bf16x8 af[4], bfr[4];
#pragma unroll
      for (int m = 0; m < 4; ++m) af[m] = *(const bf16x8*)(As + (wm + m * 16 + lr) * 64 + kk + lk);
#pragma unroll
      for (int n = 0; n < 4; ++n) bfr[n] = *(const bf16x8*)(Bs + (wn + n * 16 + lr) * 64 + kk + lk);
#pragma unroll
      for (int m = 0; m < 4; ++m)
#pragma unroll
        for (int n = 0; n < 4; ++n)
          acc[m][n] = __builtin_amdgcn_mfma_f32_16x16x32_bf16(af[m], bfr[n], acc[m][n], 0, 0, 0);
    }
    __syncthreads();
  }
  u16* wtile = swf + ((size_t)(b * 136 + tri) << 14);
#pragma unroll
  for (int m = 0; m < 4; ++m)
#pragma unroll
    for (int n = 0; n < 4; ++n)
#pragma unroll
      for (int j = 0; j < 4; ++j) {
        int rl = wm + m * 16 + (lane >> 4) * 4 + j;
        int cl = wn + n * 16 + lr;
        wtile[rl * 128 + cl] = f32_to_bf16(acc[m][n][j]);
      }
}

// ---------------- K3: softmax (+16 trailing x-blocks convert W_out -> bf16) ----------------
__global__ __launch_bounds__(256) void k_softmax(u16* __restrict__ swf, float* __restrict__ w,
                                                 const float* __restrict__ W_out,
                                                 u16* __restrict__ wob) {
  const int n = blockIdx.x, b = blockIdx.y;
  const int t = threadIdx.x;
  if (n >= NLEN) {
    int g = ((n - NLEN) * 4 + b) * 256 + t;  // 0..16383
#pragma unroll
    for (int i = 0; i < 4; ++i) {
      int e = g * 32 + i * 8;
      stage8_f32(wob + e, W_out + e);
    }
    return;
  }
  float* wrow = w + ((size_t)b * NLEN + n) * NLEN;
  const int nt = n >> 7;
  const size_t tb = ((size_t)(b * 136 + nt * (nt + 1) / 2) << 14) + ((size_t)(n & 127) << 7);
  __shared__ float srow[NLEN];
  __shared__ float red[4];
  if (n == 0) {
    for (int i = t; i < NLEN / 4; i += 256) ((float4*)wrow)[i] = float4{0, 0, 0, 0};
    if (t < 16) ((uint4*)(swf + tb))[t] = uint4{0, 0, 0, 0};
    return;
  }
  const int lane = t & 63, wid = t >> 6;
  const int nchunk = (nt + 1) * 16;
  float mx = -1e38f;
  for (int idx = t; idx < nchunk; idx += 256) {
    const int mt = idx >> 4, c = idx & 15;
    uint4 rv = *(const uint4*)(swf + tb + ((size_t)mt << 14) + c * 8);
    int m0 = mt * 128 + c * 8;
    u32 wds[4] = {rv.x, rv.y, rv.z, rv.w};
#pragma unroll
    for (int wi = 0; wi < 4; ++wi) {
      float v0 = __uint_as_float(wds[wi] << 16);
      float v1 = __uint_as_float(wds[wi] & 0xffff0000u);
      int m = m0 + wi * 2;
      srow[m] = v0; srow[m + 1] = v1;
      if (m < n) mx = fmaxf(mx, v0);
      if (m + 1 < n) mx = fmaxf(mx, v1);
    }
  }
#pragma unroll
  for (int off = 32; off; off >>= 1) mx = fmaxf(mx, __shfl_xor(mx, off));
  if (lane == 0) red[wid] = mx;
  __syncthreads();
  mx = fmaxf(fmaxf(red[0], red[1]), fmaxf(red[2], red[3]));
  float sum = 0.f;
  for (int m = t; m < n; m += 256) {
    float e = __expf(srow[m] - mx);
    srow[m] = e;
    sum += e;
  }
#pragma unroll
  for (int off = 32; off; off >>= 1) sum += __shfl_xor(sum, off);
  __syncthreads();
  if (lane == 0) red[wid] = sum;
  __syncthreads();
  float inv = 1.0f / (red[0] + red[1] + red[2] + red[3]);
  {
    int m0 = t * 8;
    float vals[8];
#pragma unroll
    for (int e = 0; e < 8; ++e) { int m = m0 + e; vals[e] = (m < n) ? srow[m] * inv : 0.f; }
    ((float4*)wrow)[t * 2] = float4{vals[0], vals[1], vals[2], vals[3]};
    ((float4*)wrow)[t * 2 + 1] = float4{vals[4], vals[5], vals[6], vals[7]};
  }
  for (int idx = t; idx < nchunk; idx += 256) {
    const int mt = idx >> 4, c = idx & 15;
    int m0 = mt * 128 + c * 8;
    u32 wo[4];
#pragma unroll
    for (int wi = 0; wi < 4; ++wi) {
      int m = m0 + wi * 2;
      float v0 = (m < n) ? srow[m] * inv : 0.f;
      float v1 = (m + 1 < n) ? srow[m + 1] * inv : 0.f;
      wo[wi] = (u32)f32_to_bf16(v0) | ((u32)f32_to_bf16(v1) << 16);
    }
    *(uint4*)(swf + tb + ((size_t)mt << 14) + c * 8) = uint4{wo[0], wo[1], wo[2], wo[3]};
  }
}

// ---------------- K4: mix, m97 structure, 2-way split-K (384 blocks, heavy first) ----------------
__global__ __launch_bounds__(256) void k_mix(const u16* __restrict__ swf,
                                             const u16* __restrict__ qt,
                                             u16* __restrict__ amix,
                                             u16* __restrict__ mix1) {
  const int j = blockIdx.x >> 4;       // 0..23, heavy first
  const int bdt = blockIdx.x & 15;
  const int b = bdt >> 2, dt = bdt & 3;
  int nt, kt0, ktn, slot;
  if (j < 16) {
    nt = 15 - (j >> 1);
    if ((j & 1) == 0) { kt0 = 0; ktn = 8; slot = 0; }
    else { kt0 = 8; ktn = nt + 1; slot = 1; }
  } else {
    nt = 23 - j; kt0 = 0; ktn = nt + 1; slot = 0;
  }
  __shared__ u16 As[128 * 64];
  __shared__ u16 Bs[128 * 64];
  const int t = threadIdx.x;
  const int lane = t & 63, wid = t >> 6;
  const int wm = (wid >> 1) * 64, wn = (wid & 1) * 64;
  const int lr = lane & 15, lk = (lane >> 4) * 8;
  const size_t tribase = (size_t)(b * 136 + nt * (nt + 1) / 2) << 14;
  const u16* bgbase = qt + (size_t)(b * DIM + dt * 128) * NLEN;
  f32x4 acc[4][4] = {};
  for (int ks = kt0 * 2; ks < ktn * 2; ++ks) {  // K-steps of 64
    const u16* ag = swf + tribase + ((size_t)(ks >> 1) << 14) + (ks & 1) * 64;
    glds_rows<32>(ag, 128, As, wid * 32, lane);
    glds_rows<32>(bgbase + ks * 64, NLEN, Bs, wid * 32, lane);
    __syncthreads();
#pragma unroll
    for (int kk = 0; kk < 64; kk += 32) {
      bf16x8 af[4], bfr[4];
#pragma unroll
      for (int m = 0; m < 4; ++m) af[m] = *(const bf16x8*)(As + (wm + m * 16 + lr) * 64 + kk + lk);
#pragma unroll
      for (int n = 0; n < 4; ++n) bfr[n] = *(const bf16x8*)(Bs + (wn + n * 16 + lr) * 64 + kk + lk);
#pragma unroll
      for (int m = 0; m < 4; ++m)
#pragma unroll
        for (int n = 0; n < 4; ++n)
          acc[m][n] = __builtin_amdgcn_mfma_f32_16x16x32_bf16(af[m], bfr[n], acc[m][n], 0, 0, 0);
    }
    __syncthreads();
  }
  u16* dst = slot ? mix1 : amix;
#pragma unroll
  for (int m = 0; m < 4; ++m)
#pragma unroll
    for (int n = 0; n < 4; ++n)
#pragma unroll
      for (int j2 = 0; j2 < 4; ++j2) {
        int row = nt * 128 + wm + m * 16 + (lane >> 4) * 4 + j2;
        int col = dt * 128 + wn + n * 16 + lr;
        dst[(size_t)(b * NLEN + row) * DIM + col] = f32_to_bf16(acc[m][n][j2]);
      }
}

// ---------------- K4b: fold slot-1 partials into amix (rows n>=1024 only) ----------------
__global__ __launch_bounds__(256) void k_fold(u16* __restrict__ amix,
                                              const u16* __restrict__ mix1) {
  const int t = threadIdx.x;
#pragma unroll
  for (int i = 0; i < 2; ++i) {
    int g = (blockIdx.x * 2 + i) * 256 + t;  // uint4 index over 4*1024*512/8
    int rowlin = g >> 6, within = g & 63;
    int b = rowlin >> 10, n = 1024 + (rowlin & 1023);
    size_t off = ((size_t)(b * NLEN + n) * DIM) + within * 8;
    uint4 a = *(const uint4*)(amix + off);
    uint4 c = *(const uint4*)(mix1 + off);
    uint4 o;
    o.x = addpk_bf16(a.x, c.x); o.y = addpk_bf16(a.y, c.y);
    o.z = addpk_bf16(a.z, c.z); o.w = addpk_bf16(a.w, c.w);
    *(uint4*)(amix + off) = o;
  }
}

// ---------------- K5: out = selu([amix,q] . wob^T), 128x64 tiles, BK=64, glds ----------------
__global__ __launch_bounds__(256) void k_out(const u16* __restrict__ amix,
                                             const u16* __restrict__ qp,
                                             const u16* __restrict__ wob,
                                             float* __restrict__ out) {
  __shared__ u16 As[128 * 64];
  __shared__ u16 Bs[64 * 64];
  const int et = blockIdx.x;   // 8 col tiles of 64
  const int rt = blockIdx.y;   // 64 row tiles of 128
  const int t = threadIdx.x;
  const int lane = t & 63, wid = t >> 6;
  const int wm = (wid >> 1) * 64, wn = (wid & 1) * 32;
  const int lr = lane & 15, lk = (lane >> 4) * 8;
  const int rbase = rt * 128;
  const u16* aMix = amix + (size_t)rbase * DIM;
  const u16* aQ = qp + (size_t)rbase * DIM;
  const u16* bW = wob + (size_t)(et * 64) * (2 * DIM);
  f32x4 acc[4][2] = {};
  for (int k0 = 0; k0 < 2 * DIM; k0 += 64) {
    const u16* ag = (k0 < DIM) ? (aMix + k0) : (aQ + (k0 - DIM));
    glds_rows<32>(ag, DIM, As, wid * 32, lane);
    glds_rows<16>(bW + k0, 2 * DIM, Bs, wid * 16, lane);
    __syncthreads();
#pragma unroll
    for (int kk = 0; kk < 64; kk += 32) {
      bf16x8 af[4], bfr[2];
#pragma unroll
      for (int m = 0; m < 4; ++m) af[m] = *(const bf16x8*)(As + (wm + m * 16 + lr) * 64 + kk + lk);
#pragma unroll
      for (int n = 0; n < 2; ++n) bfr[n] = *(const bf16x8*)(Bs + (wn + n * 16 + lr) * 64 + kk + lk);
#pragma unroll
      for (int m = 0; m < 4; ++m)
#pragma unroll
        for (int n = 0; n < 2; ++n)
          acc[m][n] = __builtin_amdgcn_mfma_f32_16x16x32_bf16(af[m], bfr[n], acc[m][n], 0, 0, 0);
    }
    __syncthreads();
  }
  const float sc = 1.0507009873554805f;
  const float al = 1.6732632423543772f;
#pragma unroll
  for (int m = 0; m < 4; ++m)
#pragma unroll
    for (int n = 0; n < 2; ++n)
#pragma unroll
      for (int j = 0; j < 4; ++j) {
        int row = rbase + wm + m * 16 + (lane >> 4) * 4 + j;
        int col = et * 64 + wn + n * 16 + lr;
        int b2 = row >> 11, n2 = row & 2047;
        float v = acc[m][n][j];
        v = (v > 0.f) ? sc * v : sc * al * (__expf(v) - 1.f);
        out[(size_t)(n2 * BATCH + b2) * DIM + col] = v;
      }
}

extern "C" void kernel_launch(void* const* d_in, const int* in_sizes, int n_in,
                              void* d_out, int out_size, void* d_ws, size_t ws_size,
                              hipStream_t stream) {
  const float* query = (const float*)d_in[0];
  const float* W_in = (const float*)d_in[1];
  const float* W_out = (const float*)d_in[2];
  float* out0 = (float*)d_out;                   // [NLEN][BATCH][DIM] f32
  float* w = out0 + (size_t)NLEN * BATCH * DIM;  // weights [BATCH][NLEN][NLEN] f32

  const size_t PSZ = (size_t)BATCH * NLEN * DIM;
  u16* qp = (u16*)d_ws;            // [B][N][D] bf16
  u16* qt = qp + PSZ;              // [B][D][N] bf16
  u16* amix = qt + PSZ;            // [B][N][D] bf16 (chunk-0 partial -> final)
  u16* mix1 = amix + PSZ;          // [B][N][D] bf16 (chunk-1 partial, rows>=1024)
  u16* swf = mix1 + PSZ;           // packed tri tiles [B][136][128][128] bf16
  u16* wob = swf + (size_t)BATCH * 136 * 16384;  // W_out bf16 [512][1024]

  dim3 blk(256);
  k_qproj<<<dim3(DIM / 128, (BATCH * NLEN) / 64), blk, 0, stream>>>(query, W_in, qp, qt);
  k_scores<<<dim3(136, BATCH), blk, 0, stream>>>(qp, swf);
  k_softmax<<<dim3(NLEN + 16, BATCH), blk, 0, stream>>>(swf, w, W_out, wob);
  k_mix<<<dim3(384), blk, 0, stream>>>(swf, qt, amix, mix1);
  k_fold<<<dim3(512), blk, 0, stream>>>(amix, mix1);
  k_out<<<dim3(8, 64), blk, 0, stream>>>(amix, qp, wob, out0);
}